// Round 7
// baseline (262.112 us; speedup 1.0000x reference)
//
#include <hip/hip_runtime.h>
#include <hip/hip_bf16.h>

#define NN 50000
#define EE 800000
#define DD 128
#define TILES (EE / 64)              // 12500
#define NB_SCAN ((NN + 255) / 256)   // 196

typedef __attribute__((ext_vector_type(8))) short bf8v;        // 8 bf16
typedef __attribute__((ext_vector_type(4))) float f4v;         // 4 f32
typedef __attribute__((ext_vector_type(4))) unsigned int u4v;  // 16B

static __device__ __forceinline__ unsigned int bpack2(float lo, float hi) {
    union { __hip_bfloat162 h2; unsigned int u; } c;
    c.h2 = __float22bfloat162_rn(float2{lo, hi});   // v_cvt_pk_bf16_f32
    return c.u;
}
static __device__ __forceinline__ u4v pack8(f4v a, f4v b) {
    u4v r;
    r[0] = bpack2(a[0], a[1]); r[1] = bpack2(a[2], a[3]);
    r[2] = bpack2(b[0], b[1]); r[3] = bpack2(b[2], b[3]);
    return r;
}
static __device__ __forceinline__ short f2bf_s(float f) {
    union { __hip_bfloat16 h; short s; } c;
    c.h = __float2bfloat16(f);
    return c.s;
}
static __device__ __forceinline__ float bf_lo(unsigned int u) {
    union { unsigned int u; float f; } c; c.u = u << 16; return c.f;
}
static __device__ __forceinline__ float bf_hi(unsigned int u) {
    union { unsigned int u; float f; } c; c.u = u & 0xffff0000u; return c.f;
}
static __device__ __forceinline__ float silu(float v) {
    return v * __builtin_amdgcn_rcpf(1.f + __expf(-v));
}

// ---- setup: weight repack (MFMA B-frag layout) + zero cnt + zero aggr ----
__global__ __launch_bounds__(256) void setup_kernel(
    const float* __restrict__ wm1, const float* __restrict__ wm2,
    const float* __restrict__ wu1, const float* __restrict__ wu2,
    short* __restrict__ out, int* __restrict__ cnt, float* __restrict__ aggr) {
    int idx = blockIdx.x * 256 + threadIdx.x;   // grid 384*256 = 98304
    {
        const float* src; int l;
        if      (idx < 32768) { src = wm1; l = idx; }
        else if (idx < 49152) { src = wm2; l = idx - 32768; }
        else if (idx < 81920) { src = wu1; l = idx - 49152; }
        else                  { src = wu2; l = idx - 81920; }
        int e    = l & 7;
        int lane = (l >> 3) & 63;
        int ntg  = (l >> 9) & 7;
        int kc   = l >> 12;
        out[idx] = f2bf_s(src[(kc * 32 + (lane >> 4) * 8 + e) * DD + ntg * 16 + (lane & 15)]);
    }
    for (int i = idx; i < NN; i += 98304) cnt[i] = 0;
    f4v z = (f4v){0.f, 0.f, 0.f, 0.f};
    for (int i = idx; i < NN * DD / 4; i += 98304) ((f4v*)aggr)[i] = z;
}

// ---------------- counting sort by destination row ----------------
__global__ __launch_bounds__(256) void hist_kernel(const int* __restrict__ ei,
                                                   int* __restrict__ cnt) {
    int e = blockIdx.x * 256 + threadIdx.x;
    if (e < EE) atomicAdd(&cnt[ei[e]], 1);
}

__global__ __launch_bounds__(256) void scanA_kernel(const int* __restrict__ cnt,
                                                    int* __restrict__ bsum) {
    __shared__ int sd[256];
    int t = threadIdx.x;
    int i = blockIdx.x * 256 + t;
    sd[t] = (i < NN) ? cnt[i] : 0;
    __syncthreads();
    for (int off = 128; off > 0; off >>= 1) {
        if (t < off) sd[t] += sd[t + off];
        __syncthreads();
    }
    if (t == 0) bsum[blockIdx.x] = sd[0];
}

__global__ __launch_bounds__(256) void scanB_kernel(const int* __restrict__ bsum,
                                                    int* __restrict__ bscan) {
    __shared__ int sd[256];
    int t = threadIdx.x;
    int v = (t < NB_SCAN) ? bsum[t] : 0;
    sd[t] = v;
    __syncthreads();
    for (int off = 1; off < 256; off <<= 1) {
        int u = (t >= off) ? sd[t - off] : 0;
        __syncthreads();
        sd[t] += u;
        __syncthreads();
    }
    if (t < NB_SCAN) bscan[t] = sd[t] - v;   // exclusive
}

// scanC + rows_fill fused: cursor[i] and rows[cursor[i]..cursor[i]+cnt[i])
__global__ __launch_bounds__(256) void scanC_kernel(const int* __restrict__ cnt,
                                                    const int* __restrict__ bscan,
                                                    int* __restrict__ cursor,
                                                    int* __restrict__ rows) {
    __shared__ int sd[256];
    int t = threadIdx.x;
    int i = blockIdx.x * 256 + t;
    int v = (i < NN) ? cnt[i] : 0;
    sd[t] = v;
    __syncthreads();
    for (int off = 1; off < 256; off <<= 1) {
        int u = (t >= off) ? sd[t - off] : 0;
        __syncthreads();
        sd[t] += u;
        __syncthreads();
    }
    if (i < NN) {
        int c0 = bscan[blockIdx.x] + sd[t] - v;
        cursor[i] = c0;
        for (int k = 0; k < v; ++k) rows[c0 + k] = i;
    }
}

__global__ __launch_bounds__(256) void scatter_col_atomic_kernel(const int* __restrict__ ei,
                                                                 int* __restrict__ cursor,
                                                                 int* __restrict__ srtc) {
    int e = blockIdx.x * 256 + threadIdx.x;
    if (e < EE) {
        int pos = atomicAdd(&cursor[ei[e]], 1);
        srtc[pos] = ei[EE + e];
    }
}

// ---------------- P/Q precompute: P = bf16(x@W1top + bm1), Q = bf16(x@W1bot) ----------------
__global__ __launch_bounds__(256) void pq_kernel(
    const float* __restrict__ x,
    const short* __restrict__ W1f, const float* __restrict__ bm1,
    short* __restrict__ P, short* __restrict__ Q)
{
    __shared__ char smem[32768];     // As [64][128]bf16 @0 (16KB) -> Pst @0 ; Qst @16384
    const int tid = threadIdx.x;
    const int w = tid >> 6, lane = tid & 63;
    const int rbase = blockIdx.x * 64;
    const int rloc = tid >> 2, s = tid & 3;

    {   // stage x tile f32 -> bf16 LDS
        int rg = rbase + rloc;
        int rgc = rg < NN ? rg : NN - 1;
        const float* xr = x + (size_t)rgc * DD + s * 32;
        int swz = (rloc & 7) << 4;
        #pragma unroll
        for (int j = 0; j < 4; ++j) {
            f4v a0 = *(const f4v*)(xr + j * 8);
            f4v a1 = *(const f4v*)(xr + j * 8 + 4);
            *(u4v*)(smem + ((rloc * 256 + s * 64 + j * 16) ^ swz)) = pack8(a0, a1);
        }
    }

    bf8v w1t[4][2], w1b[4][2];
    #pragma unroll
    for (int kc = 0; kc < 4; ++kc)
        #pragma unroll
        for (int nt = 0; nt < 2; ++nt) {
            w1t[kc][nt] = *(const bf8v*)(W1f + (((kc * 8) + (w * 2 + nt)) * 64 + lane) * 8);
            w1b[kc][nt] = *(const bf8v*)(W1f + ((((kc + 4) * 8) + (w * 2 + nt)) * 64 + lane) * 8);
        }
    __syncthreads();

    f4v accP[4][2], accQ[4][2];
    #pragma unroll
    for (int mt = 0; mt < 4; ++mt)
        #pragma unroll
        for (int nt = 0; nt < 2; ++nt) {
            accP[mt][nt] = (f4v){0.f, 0.f, 0.f, 0.f};
            accQ[mt][nt] = (f4v){0.f, 0.f, 0.f, 0.f};
        }
    #pragma unroll
    for (int kc = 0; kc < 4; ++kc) {
        bf8v a[4];
        int kb = kc * 64 + (lane >> 4) * 16;
        #pragma unroll
        for (int mt = 0; mt < 4; ++mt) {
            int row = mt * 16 + (lane & 15);
            a[mt] = *(const bf8v*)(smem + ((row * 256 + kb) ^ ((row & 7) << 4)));
        }
        #pragma unroll
        for (int mt = 0; mt < 4; ++mt)
            #pragma unroll
            for (int nt = 0; nt < 2; ++nt) {
                accP[mt][nt] = __builtin_amdgcn_mfma_f32_16x16x32_bf16(a[mt], w1t[kc][nt], accP[mt][nt], 0, 0, 0);
                accQ[mt][nt] = __builtin_amdgcn_mfma_f32_16x16x32_bf16(a[mt], w1b[kc][nt], accQ[mt][nt], 0, 0, 0);
            }
    }
    __syncthreads();   // done reading As

    int col0 = w * 32 + (lane & 15);
    float b1a = bm1[col0], b1b = bm1[col0 + 16];
    #pragma unroll
    for (int mt = 0; mt < 4; ++mt)
        #pragma unroll
        for (int nt = 0; nt < 2; ++nt) {
            float bb = nt ? b1b : b1a;
            int col = col0 + nt * 16;
            #pragma unroll
            for (int r = 0; r < 4; ++r) {
                int row = mt * 16 + (lane >> 4) * 4 + r;
                int off = (row * 256 + col * 2) ^ ((row & 7) << 4);
                *(short*)(smem + off)         = f2bf_s(accP[mt][nt][r] + bb);
                *(short*)(smem + 16384 + off) = f2bf_s(accQ[mt][nt][r]);
            }
        }
    __syncthreads();

    {   // coalesced store P,Q
        int rg = rbase + rloc;
        if (rg < NN) {
            int swz = (rloc & 7) << 4;
            #pragma unroll
            for (int j = 0; j < 4; ++j) {
                int off = (rloc * 256 + s * 64 + j * 16) ^ swz;
                *(u4v*)(P + (size_t)rg * DD + s * 32 + j * 8) = *(const u4v*)(smem + off);
                *(u4v*)(Q + (size_t)rg * DD + s * 32 + j * 8) = *(const u4v*)(smem + 16384 + off);
            }
        }
    }
}

// ---------------- edge kernel: one 64-edge tile per block, Ms overlays Hs ----------------
// h = silu(P[r]+Q[c]); msg = h@W2 + bm2; segmented scatter-add over sorted dests
__global__ __launch_bounds__(256, 8) void edge_kernel(
    const short* __restrict__ P, const short* __restrict__ Q,
    const int* __restrict__ rows, const int* __restrict__ srtc,
    const int* __restrict__ ei, int use_sorted,
    const short* __restrict__ W2f, const float* __restrict__ bm2,
    float* __restrict__ aggr)
{
    __shared__ char smem[16384 + 256];
    char* Hs = smem;                 // [64][128] bf16 swizzled; reused as Ms after GEMM2
    int* rows_s = (int*)(smem + 16384);

    const int tid = threadIdx.x;
    const int w = tid >> 6, lane = tid & 63;
    const int rloc = tid >> 2, s = tid & 3;

    // ---- stage: gather P[r], Q[c], h = silu(P+Q) -> Hs ----
    {
        int eg = blockIdx.x * 64 + rloc;
        int r, c;
        if (use_sorted) { r = rows[eg]; c = srtc[eg]; }
        else            { r = ei[eg];   c = ei[EE + eg]; }
        if (s == 0) rows_s[rloc] = r;
        const u4v* pr = (const u4v*)(P + (size_t)r * DD + s * 32);
        const u4v* qr = (const u4v*)(Q + (size_t)c * DD + s * 32);
        int swz = (rloc & 7) << 4;
        #pragma unroll
        for (int j = 0; j < 4; ++j) {
            u4v pj = pr[j], qj = qr[j];
            u4v hv;
            #pragma unroll
            for (int k2 = 0; k2 < 4; ++k2) {
                float lo = silu(bf_lo(pj[k2]) + bf_lo(qj[k2]));
                float hi = silu(bf_hi(pj[k2]) + bf_hi(qj[k2]));
                hv[k2] = bpack2(lo, hi);
            }
            *(u4v*)(Hs + ((rloc * 256 + s * 64 + j * 16) ^ swz)) = hv;
        }
    }

    // weight fragments (independent of stage; overlaps gather latency)
    bf8v w2f[4][2];
    #pragma unroll
    for (int kc = 0; kc < 4; ++kc)
        #pragma unroll
        for (int nt = 0; nt < 2; ++nt)
            w2f[kc][nt] = *(const bf8v*)(W2f + (((kc * 8) + (w * 2 + nt)) * 64 + lane) * 8);
    int col0 = w * 32 + (lane & 15);
    float b2a = bm2[col0], b2b = bm2[col0 + 16];

    __syncthreads();   // Hs ready

    // ---- GEMM2: [64x128] @ [128x32-slice] ----
    f4v acc2[4][2];
    #pragma unroll
    for (int mt = 0; mt < 4; ++mt)
        #pragma unroll
        for (int nt = 0; nt < 2; ++nt)
            acc2[mt][nt] = (f4v){0.f, 0.f, 0.f, 0.f};
    #pragma unroll
    for (int kc = 0; kc < 4; ++kc) {
        bf8v a[4];
        int kb = kc * 64 + (lane >> 4) * 16;
        #pragma unroll
        for (int mt = 0; mt < 4; ++mt) {
            int row = mt * 16 + (lane & 15);
            a[mt] = *(const bf8v*)(Hs + ((row * 256 + kb) ^ ((row & 7) << 4)));
        }
        #pragma unroll
        for (int mt = 0; mt < 4; ++mt)
            #pragma unroll
            for (int nt = 0; nt < 2; ++nt)
                acc2[mt][nt] = __builtin_amdgcn_mfma_f32_16x16x32_bf16(a[mt], w2f[kc][nt], acc2[mt][nt], 0, 0, 0);
    }
    __syncthreads();   // all waves done reading Hs; overlay Ms

    // ---- park messages (bias + bf16) into Ms (= Hs) ----
    #pragma unroll
    for (int mt = 0; mt < 4; ++mt)
        #pragma unroll
        for (int nt = 0; nt < 2; ++nt) {
            int col = col0 + nt * 16;
            float bb = nt ? b2b : b2a;
            #pragma unroll
            for (int r = 0; r < 4; ++r) {
                int row = mt * 16 + (lane >> 4) * 4 + r;
                *(short*)(Hs + ((row * 256 + col * 2) ^ ((row & 7) << 4))) = f2bf_s(acc2[mt][nt][r] + bb);
            }
        }
    __syncthreads();   // Ms + rows_s ready

    // ---- segmented reduce over sorted dests: 128 threads, col-pair each, u32 reads ----
    if (tid < 128) {
        int pp = tid & 63;             // col pair (cols 2pp, 2pp+1)
        int hh = tid >> 6;             // row half
        int cbyte = pp * 4;
        int r0 = hh * 32;
        int cur = rows_s[r0];
        float run0 = 0.f, run1 = 0.f;
        #pragma unroll 4
        for (int k = 0; k < 32; ++k) {
            int row = r0 + k;
            int d = rows_s[row];
            unsigned int uv = *(const unsigned int*)(Hs + ((row * 256 + cbyte) ^ ((row & 7) << 4)));
            if (d != cur) {
                unsafeAtomicAdd(aggr + (size_t)cur * DD + pp * 2,     run0);
                unsafeAtomicAdd(aggr + (size_t)cur * DD + pp * 2 + 1, run1);
                run0 = 0.f; run1 = 0.f; cur = d;
            }
            run0 += bf_lo(uv);
            run1 += bf_hi(uv);
        }
        unsafeAtomicAdd(aggr + (size_t)cur * DD + pp * 2,     run0);
        unsafeAtomicAdd(aggr + (size_t)cur * DD + pp * 2 + 1, run1);
    }
}

// ---------------- node kernel: update MLP + residual + LayerNorm ----------------
__global__ __launch_bounds__(256, 4) void node_kernel(
    const float* __restrict__ x, const float* __restrict__ aggr,
    const short* __restrict__ U1f, const short* __restrict__ U2f,
    const float* __restrict__ bu1, const float* __restrict__ bu2,
    const float* __restrict__ gmm, const float* __restrict__ bta,
    float* __restrict__ out)
{
    __shared__ char smem[64 * 512 + 2048];
    char* As = smem;
    float* ps  = (float*)(smem + 64 * 512);
    float* ps2 = ps + 256;

    const int tid = threadIdx.x;
    const int w = tid >> 6, lane = tid & 63;
    const int rbase = blockIdx.x * 64;
    const int rloc = tid >> 2, s = tid & 3;

    {
        int rg = rbase + rloc;
        int rgc = rg < NN ? rg : 0;
        const float* xr = x + (size_t)rgc * DD + s * 32;
        const float* ar = aggr + (size_t)rgc * DD + s * 32;
        int swz = (rloc & 7) << 4;
        #pragma unroll
        for (int i2 = 0; i2 < 4; ++i2) {
            f4v a0 = *(const f4v*)(xr + i2 * 8);
            f4v a1 = *(const f4v*)(xr + i2 * 8 + 4);
            int addr = rloc * 512 + s * 64 + i2 * 16;
            *(u4v*)(As + (addr ^ swz)) = pack8(a0, a1);
            f4v b0 = *(const f4v*)(ar + i2 * 8);
            f4v b1 = *(const f4v*)(ar + i2 * 8 + 4);
            int addr2 = rloc * 512 + 256 + s * 64 + i2 * 16;
            *(u4v*)(As + (addr2 ^ swz)) = pack8(b0, b1);
        }
    }

    bf8v u1f[8][2], u2f[4][2];
    #pragma unroll
    for (int kc = 0; kc < 8; ++kc)
        #pragma unroll
        for (int nt = 0; nt < 2; ++nt)
            u1f[kc][nt] = *(const bf8v*)(U1f + (((kc * 8) + (w * 2 + nt)) * 64 + lane) * 8);
    #pragma unroll
    for (int kc = 0; kc < 4; ++kc)
        #pragma unroll
        for (int nt = 0; nt < 2; ++nt)
            u2f[kc][nt] = *(const bf8v*)(U2f + (((kc * 8) + (w * 2 + nt)) * 64 + lane) * 8);

    __syncthreads();

    f4v acc[4][2];
    #pragma unroll
    for (int mt = 0; mt < 4; ++mt)
        #pragma unroll
        for (int nt = 0; nt < 2; ++nt)
            acc[mt][nt] = (f4v){0.f, 0.f, 0.f, 0.f};
    #pragma unroll
    for (int kc = 0; kc < 8; ++kc) {
        bf8v a[4];
        int kb = kc * 64 + (lane >> 4) * 16;
        #pragma unroll
        for (int mt = 0; mt < 4; ++mt) {
            int row = mt * 16 + (lane & 15);
            a[mt] = *(const bf8v*)(As + ((row * 512 + kb) ^ ((row & 7) << 4)));
        }
        #pragma unroll
        for (int mt = 0; mt < 4; ++mt)
            #pragma unroll
            for (int nt = 0; nt < 2; ++nt)
                acc[mt][nt] = __builtin_amdgcn_mfma_f32_16x16x32_bf16(a[mt], u1f[kc][nt], acc[mt][nt], 0, 0, 0);
    }
    __syncthreads();

    int col0 = w * 32 + (lane & 15);
    float b1a = bu1[col0], b1b = bu1[col0 + 16];
    #pragma unroll
    for (int mt = 0; mt < 4; ++mt)
        #pragma unroll
        for (int nt = 0; nt < 2; ++nt) {
            float bb = nt ? b1b : b1a;
            int col = col0 + nt * 16;
            #pragma unroll
            for (int r = 0; r < 4; ++r) {
                float v = silu(acc[mt][nt][r] + bb);
                int row = mt * 16 + (lane >> 4) * 4 + r;
                *(short*)(As + ((row * 256 + col * 2) ^ ((row & 7) << 4))) = f2bf_s(v);
            }
        }
    __syncthreads();

    f4v acc2[4][2];
    #pragma unroll
    for (int mt = 0; mt < 4; ++mt)
        #pragma unroll
        for (int nt = 0; nt < 2; ++nt)
            acc2[mt][nt] = (f4v){0.f, 0.f, 0.f, 0.f};
    #pragma unroll
    for (int kc = 0; kc < 4; ++kc) {
        bf8v a[4];
        int kb = kc * 64 + (lane >> 4) * 16;
        #pragma unroll
        for (int mt = 0; mt < 4; ++mt) {
            int row = mt * 16 + (lane & 15);
            a[mt] = *(const bf8v*)(As + ((row * 256 + kb) ^ ((row & 7) << 4)));
        }
        #pragma unroll
        for (int mt = 0; mt < 4; ++mt)
            #pragma unroll
            for (int nt = 0; nt < 2; ++nt)
                acc2[mt][nt] = __builtin_amdgcn_mfma_f32_16x16x32_bf16(a[mt], u2f[kc][nt], acc2[mt][nt], 0, 0, 0);
    }
    __syncthreads();

    // ---- park msg = acc2 + bias (f32, no x) ----
    float b2a = bu2[col0], b2b = bu2[col0 + 16];
    #pragma unroll
    for (int mt = 0; mt < 4; ++mt)
        #pragma unroll
        for (int nt = 0; nt < 2; ++nt) {
            int col = col0 + nt * 16;
            float bb = nt ? b2b : b2a;
            #pragma unroll
            for (int r = 0; r < 4; ++r) {
                int rowl = mt * 16 + (lane >> 4) * 4 + r;
                *(float*)(As + ((rowl * 512 + col * 4) ^ ((rowl & 7) << 4))) = acc2[mt][nt][r] + bb;
            }
        }
    __syncthreads();

    // ---- residual (coalesced x) + LN partials, write y back ----
    {
        int rg = rbase + rloc;
        int rgc = rg < NN ? rg : 0;
        const f4v* xr = (const f4v*)(x + (size_t)rgc * DD + s * 32);
        float s1 = 0.f, s2 = 0.f;
        #pragma unroll
        for (int i = 0; i < 8; ++i) {
            int off = (rloc * 512 + s * 128 + i * 16) ^ ((rloc & 7) << 4);
            f4v v = *(const f4v*)(As + off);
            f4v xv = xr[i];
            f4v y;
            #pragma unroll
            for (int j = 0; j < 4; ++j) {
                y[j] = v[j] + xv[j];
                s1 += y[j];
                s2 += y[j] * y[j];
            }
            *(f4v*)(As + off) = y;
        }
        ps[rloc * 4 + s] = s1;
        ps2[rloc * 4 + s] = s2;
    }
    __syncthreads();
    {
        float fs  = ps[rloc * 4] + ps[rloc * 4 + 1] + ps[rloc * 4 + 2] + ps[rloc * 4 + 3];
        float fs2 = ps2[rloc * 4] + ps2[rloc * 4 + 1] + ps2[rloc * 4 + 2] + ps2[rloc * 4 + 3];
        float mu  = fs * (1.f / 128.f);
        float var = fs2 * (1.f / 128.f) - mu * mu;
        float inv = rsqrtf(var + 1e-5f);
        int rg = rbase + rloc;
        if (rg < NN) {
            #pragma unroll
            for (int i = 0; i < 8; ++i) {
                int col = s * 32 + i * 4;
                f4v v  = *(const f4v*)(As + ((rloc * 512 + col * 4) ^ ((rloc & 7) << 4)));
                f4v gg = *(const f4v*)(gmm + col);
                f4v bb = *(const f4v*)(bta + col);
                f4v o;
                #pragma unroll
                for (int j = 0; j < 4; ++j)
                    o[j] = (v[j] - mu) * inv * gg[j] + bb[j];
                *(f4v*)(out + (size_t)rg * DD + col) = o;
            }
        }
    }
}

extern "C" void kernel_launch(void* const* d_in, const int* in_sizes, int n_in,
                              void* d_out, int out_size, void* d_ws, size_t ws_size,
                              hipStream_t stream) {
    const float* x    = (const float*)d_in[0];
    const int*   ei   = (const int*)d_in[1];
    const float* wm1  = (const float*)d_in[2];
    const float* bm1  = (const float*)d_in[3];
    const float* wm2  = (const float*)d_in[4];
    const float* bm2  = (const float*)d_in[5];
    const float* wu1  = (const float*)d_in[6];
    const float* bu1  = (const float*)d_in[7];
    const float* wu2  = (const float*)d_in[8];
    const float* bu2  = (const float*)d_in[9];
    const float* gmm  = (const float*)d_in[10];
    const float* bta  = (const float*)d_in[11];
    float* out = (float*)d_out;

    // ws layout (bytes)
    const size_t off_P     = 0;                       // 12,800,000 (bf16 [N][128])
    const size_t off_Q     = 12800000;                // 12,800,000
    const size_t off_frags = 25600000;                // 196,608
    const size_t off_cnt   = 25796608;                // 200,000
    const size_t off_cur   = 25996608;                // 200,000
    const size_t off_bsum  = 26196608;                // 1,024
    const size_t off_bscan = 26197632;                // 1,024
    const size_t off_rows  = 26198656;                // 3,200,000
    const size_t off_srtc  = 29398656;                // 3,200,000
    const size_t need_sort = 32598656;

    char* wsB = (char*)d_ws;
    short* P    = (short*)(wsB + off_P);
    short* Q    = (short*)(wsB + off_Q);
    short* Wf   = (short*)(wsB + off_frags);   // [W1f | W2f | U1f | U2f]
    short* W1f  = Wf;
    short* W2f  = Wf + 32768;
    short* U1f  = Wf + 49152;
    short* U2f  = Wf + 81920;
    int*   cnt    = (int*)(wsB + off_cnt);
    int*   cursor = (int*)(wsB + off_cur);
    int*   bsum   = (int*)(wsB + off_bsum);
    int*   bscan  = (int*)(wsB + off_bscan);
    int*   rows   = (int*)(wsB + off_rows);
    int*   srtc   = (int*)(wsB + off_srtc);

    // aggr lives in d_out: edge atomics complete before node; node block b reads only
    // its own aggr rows (staged before any out write); blocks own disjoint rows.
    float* aggr = (float*)d_out;

    setup_kernel<<<384, 256, 0, stream>>>(wm1, wm2, wu1, wu2, Wf, cnt, aggr);
    pq_kernel<<<(NN + 63) / 64, 256, 0, stream>>>(x, W1f, bm1, P, Q);

    int use_sorted = 0;
    if (ws_size >= need_sort) {
        hist_kernel<<<(EE + 255) / 256, 256, 0, stream>>>(ei, cnt);
        scanA_kernel<<<NB_SCAN, 256, 0, stream>>>(cnt, bsum);
        scanB_kernel<<<1, 256, 0, stream>>>(bsum, bscan);
        scanC_kernel<<<NB_SCAN, 256, 0, stream>>>(cnt, bscan, cursor, rows);
        scatter_col_atomic_kernel<<<(EE + 255) / 256, 256, 0, stream>>>(ei, cursor, srtc);
        use_sorted = 1;
    }

    edge_kernel<<<TILES, 256, 0, stream>>>(P, Q, rows, srtc, ei, use_sorted, W2f, bm2, aggr);
    node_kernel<<<(NN + 63) / 64, 256, 0, stream>>>(x, aggr, U1f, U2f, bu1, bu2, gmm, bta, out);
}

// Round 8
// 196.551 us; speedup vs baseline: 1.3336x; 1.3336x over previous
//
#include <hip/hip_runtime.h>
#include <hip/hip_bf16.h>

#define NN 50000
#define EE 800000
#define DD 128
#define TILES (EE / 64)              // 12500
#define NB_SCAN ((NN + 255) / 256)   // 196

typedef __attribute__((ext_vector_type(8))) short bf8v;        // 8 bf16
typedef __attribute__((ext_vector_type(4))) float f4v;         // 4 f32
typedef __attribute__((ext_vector_type(4))) unsigned int u4v;  // 16B

static __device__ __forceinline__ unsigned int bpack2(float lo, float hi) {
    union { __hip_bfloat162 h2; unsigned int u; } c;
    c.h2 = __float22bfloat162_rn(float2{lo, hi});   // v_cvt_pk_bf16_f32
    return c.u;
}
static __device__ __forceinline__ u4v pack8(f4v a, f4v b) {
    u4v r;
    r[0] = bpack2(a[0], a[1]); r[1] = bpack2(a[2], a[3]);
    r[2] = bpack2(b[0], b[1]); r[3] = bpack2(b[2], b[3]);
    return r;
}
static __device__ __forceinline__ short f2bf_s(float f) {
    union { __hip_bfloat16 h; short s; } c;
    c.h = __float2bfloat16(f);
    return c.s;
}
static __device__ __forceinline__ float bf_lo(unsigned int u) {
    union { unsigned int u; float f; } c; c.u = u << 16; return c.f;
}
static __device__ __forceinline__ float bf_hi(unsigned int u) {
    union { unsigned int u; float f; } c; c.u = u & 0xffff0000u; return c.f;
}
static __device__ __forceinline__ float silu(float v) {
    return v * __builtin_amdgcn_rcpf(1.f + __expf(-v));
}

// ---- setup: weight repack (MFMA B-frag layout) + zero cnt + zero aggr ----
__global__ __launch_bounds__(256) void setup_kernel(
    const float* __restrict__ wm1, const float* __restrict__ wm2,
    const float* __restrict__ wu1, const float* __restrict__ wu2,
    short* __restrict__ out, int* __restrict__ cnt, float* __restrict__ aggr) {
    int idx = blockIdx.x * 256 + threadIdx.x;   // grid 384*256 = 98304
    {
        const float* src; int l;
        if      (idx < 32768) { src = wm1; l = idx; }
        else if (idx < 49152) { src = wm2; l = idx - 32768; }
        else if (idx < 81920) { src = wu1; l = idx - 49152; }
        else                  { src = wu2; l = idx - 81920; }
        int e    = l & 7;
        int lane = (l >> 3) & 63;
        int ntg  = (l >> 9) & 7;
        int kc   = l >> 12;
        out[idx] = f2bf_s(src[(kc * 32 + (lane >> 4) * 8 + e) * DD + ntg * 16 + (lane & 15)]);
    }
    for (int i = idx; i < NN; i += 98304) cnt[i] = 0;
    f4v z = (f4v){0.f, 0.f, 0.f, 0.f};
    for (int i = idx; i < NN * DD / 4; i += 98304) ((f4v*)aggr)[i] = z;
}

// ---------------- counting sort by destination row ----------------
__global__ __launch_bounds__(256) void hist_rank_kernel(const int* __restrict__ ei,
                                                        int* __restrict__ cnt,
                                                        int* __restrict__ rank) {
    int e = blockIdx.x * 256 + threadIdx.x;
    if (e < EE) rank[e] = atomicAdd(&cnt[ei[e]], 1);
}

__global__ __launch_bounds__(256) void scanA_kernel(const int* __restrict__ cnt,
                                                    int* __restrict__ bsum) {
    __shared__ int sd[256];
    int t = threadIdx.x;
    int i = blockIdx.x * 256 + t;
    sd[t] = (i < NN) ? cnt[i] : 0;
    __syncthreads();
    for (int off = 128; off > 0; off >>= 1) {
        if (t < off) sd[t] += sd[t + off];
        __syncthreads();
    }
    if (t == 0) bsum[blockIdx.x] = sd[0];
}

__global__ __launch_bounds__(256) void scanB_kernel(const int* __restrict__ bsum,
                                                    int* __restrict__ bscan) {
    __shared__ int sd[256];
    int t = threadIdx.x;
    int v = (t < NB_SCAN) ? bsum[t] : 0;
    sd[t] = v;
    __syncthreads();
    for (int off = 1; off < 256; off <<= 1) {
        int u = (t >= off) ? sd[t - off] : 0;
        __syncthreads();
        sd[t] += u;
        __syncthreads();
    }
    if (t < NB_SCAN) bscan[t] = sd[t] - v;   // exclusive
}

// scanC + rows_fill fused: cursor[i]; rows[cursor[i] .. cursor[i]+cnt[i])
__global__ __launch_bounds__(256) void scanC_kernel(const int* __restrict__ cnt,
                                                    const int* __restrict__ bscan,
                                                    int* __restrict__ cursor,
                                                    int* __restrict__ rows) {
    __shared__ int sd[256];
    int t = threadIdx.x;
    int i = blockIdx.x * 256 + t;
    int v = (i < NN) ? cnt[i] : 0;
    sd[t] = v;
    __syncthreads();
    for (int off = 1; off < 256; off <<= 1) {
        int u = (t >= off) ? sd[t - off] : 0;
        __syncthreads();
        sd[t] += u;
        __syncthreads();
    }
    if (i < NN) {
        int c0 = bscan[blockIdx.x] + sd[t] - v;
        cursor[i] = c0;
        for (int k = 0; k < v; ++k) rows[c0 + k] = i;
    }
}

__global__ __launch_bounds__(256) void scatter_col_rank_kernel(const int* __restrict__ ei,
                                                               const int* __restrict__ cursor,
                                                               const int* __restrict__ rank,
                                                               int* __restrict__ srtc) {
    int e = blockIdx.x * 256 + threadIdx.x;
    if (e < EE) srtc[cursor[ei[e]] + rank[e]] = ei[EE + e];
}

__global__ __launch_bounds__(256) void scatter_col_atomic_kernel(const int* __restrict__ ei,
                                                                 int* __restrict__ cursor,
                                                                 int* __restrict__ srtc) {
    int e = blockIdx.x * 256 + threadIdx.x;
    if (e < EE) {
        int pos = atomicAdd(&cursor[ei[e]], 1);
        srtc[pos] = ei[EE + e];
    }
}

// ---------------- P/Q precompute: P = bf16(x@W1top + bm1), Q = bf16(x@W1bot) ----------------
__global__ __launch_bounds__(256) void pq_kernel(
    const float* __restrict__ x,
    const short* __restrict__ W1f, const float* __restrict__ bm1,
    short* __restrict__ P, short* __restrict__ Q)
{
    __shared__ char smem[32768];     // As [64][128]bf16 @0 (16KB) -> Pst @0 ; Qst @16384
    const int tid = threadIdx.x;
    const int w = tid >> 6, lane = tid & 63;
    const int rbase = blockIdx.x * 64;
    const int rloc = tid >> 2, s = tid & 3;

    {   // stage x tile f32 -> bf16 LDS
        int rg = rbase + rloc;
        int rgc = rg < NN ? rg : NN - 1;
        const float* xr = x + (size_t)rgc * DD + s * 32;
        int swz = (rloc & 7) << 4;
        #pragma unroll
        for (int j = 0; j < 4; ++j) {
            f4v a0 = *(const f4v*)(xr + j * 8);
            f4v a1 = *(const f4v*)(xr + j * 8 + 4);
            *(u4v*)(smem + ((rloc * 256 + s * 64 + j * 16) ^ swz)) = pack8(a0, a1);
        }
    }

    bf8v w1t[4][2], w1b[4][2];
    #pragma unroll
    for (int kc = 0; kc < 4; ++kc)
        #pragma unroll
        for (int nt = 0; nt < 2; ++nt) {
            w1t[kc][nt] = *(const bf8v*)(W1f + (((kc * 8) + (w * 2 + nt)) * 64 + lane) * 8);
            w1b[kc][nt] = *(const bf8v*)(W1f + ((((kc + 4) * 8) + (w * 2 + nt)) * 64 + lane) * 8);
        }
    __syncthreads();

    f4v accP[4][2], accQ[4][2];
    #pragma unroll
    for (int mt = 0; mt < 4; ++mt)
        #pragma unroll
        for (int nt = 0; nt < 2; ++nt) {
            accP[mt][nt] = (f4v){0.f, 0.f, 0.f, 0.f};
            accQ[mt][nt] = (f4v){0.f, 0.f, 0.f, 0.f};
        }
    #pragma unroll
    for (int kc = 0; kc < 4; ++kc) {
        bf8v a[4];
        int kb = kc * 64 + (lane >> 4) * 16;
        #pragma unroll
        for (int mt = 0; mt < 4; ++mt) {
            int row = mt * 16 + (lane & 15);
            a[mt] = *(const bf8v*)(smem + ((row * 256 + kb) ^ ((row & 7) << 4)));
        }
        #pragma unroll
        for (int mt = 0; mt < 4; ++mt)
            #pragma unroll
            for (int nt = 0; nt < 2; ++nt) {
                accP[mt][nt] = __builtin_amdgcn_mfma_f32_16x16x32_bf16(a[mt], w1t[kc][nt], accP[mt][nt], 0, 0, 0);
                accQ[mt][nt] = __builtin_amdgcn_mfma_f32_16x16x32_bf16(a[mt], w1b[kc][nt], accQ[mt][nt], 0, 0, 0);
            }
    }
    __syncthreads();   // done reading As

    int col0 = w * 32 + (lane & 15);
    float b1a = bm1[col0], b1b = bm1[col0 + 16];
    #pragma unroll
    for (int mt = 0; mt < 4; ++mt)
        #pragma unroll
        for (int nt = 0; nt < 2; ++nt) {
            float bb = nt ? b1b : b1a;
            int col = col0 + nt * 16;
            #pragma unroll
            for (int r = 0; r < 4; ++r) {
                int row = mt * 16 + (lane >> 4) * 4 + r;
                int off = (row * 256 + col * 2) ^ ((row & 7) << 4);
                *(short*)(smem + off)         = f2bf_s(accP[mt][nt][r] + bb);
                *(short*)(smem + 16384 + off) = f2bf_s(accQ[mt][nt][r]);
            }
        }
    __syncthreads();

    {   // coalesced store P,Q
        int rg = rbase + rloc;
        if (rg < NN) {
            int swz = (rloc & 7) << 4;
            #pragma unroll
            for (int j = 0; j < 4; ++j) {
                int off = (rloc * 256 + s * 64 + j * 16) ^ swz;
                *(u4v*)(P + (size_t)rg * DD + s * 32 + j * 8) = *(const u4v*)(smem + off);
                *(u4v*)(Q + (size_t)rg * DD + s * 32 + j * 8) = *(const u4v*)(smem + 16384 + off);
            }
        }
    }
}

// ---------------- edge kernel: one 64-edge tile per block, Ms overlays Hs ----------------
// h = silu(P[r]+Q[c]); msg = h@W2 + bm2; segmented scatter-add over sorted dests
__global__ __launch_bounds__(256, 8) void edge_kernel(
    const short* __restrict__ P, const short* __restrict__ Q,
    const int* __restrict__ rows, const int* __restrict__ srtc,
    const int* __restrict__ ei, int use_sorted,
    const short* __restrict__ W2f, const float* __restrict__ bm2,
    float* __restrict__ aggr)
{
    __shared__ char smem[16384 + 256];
    char* Hs = smem;                 // [64][128] bf16 swizzled; reused as Ms after GEMM2
    int* rows_s = (int*)(smem + 16384);

    const int tid = threadIdx.x;
    const int w = tid >> 6, lane = tid & 63;
    const int rloc = tid >> 2, s = tid & 3;

    // ---- stage: gather P[r], Q[c], h = silu(P+Q) -> Hs ----
    {
        int eg = blockIdx.x * 64 + rloc;
        int r, c;
        if (use_sorted) { r = rows[eg]; c = srtc[eg]; }
        else            { r = ei[eg];   c = ei[EE + eg]; }
        if (s == 0) rows_s[rloc] = r;
        const u4v* pr = (const u4v*)(P + (size_t)r * DD + s * 32);
        const u4v* qr = (const u4v*)(Q + (size_t)c * DD + s * 32);
        int swz = (rloc & 7) << 4;
        #pragma unroll
        for (int j = 0; j < 4; ++j) {
            u4v pj = pr[j], qj = qr[j];
            u4v hv;
            #pragma unroll
            for (int k2 = 0; k2 < 4; ++k2) {
                float lo = silu(bf_lo(pj[k2]) + bf_lo(qj[k2]));
                float hi = silu(bf_hi(pj[k2]) + bf_hi(qj[k2]));
                hv[k2] = bpack2(lo, hi);
            }
            *(u4v*)(Hs + ((rloc * 256 + s * 64 + j * 16) ^ swz)) = hv;
        }
    }

    // weight fragments (independent of stage; overlaps gather latency)
    bf8v w2f[4][2];
    #pragma unroll
    for (int kc = 0; kc < 4; ++kc)
        #pragma unroll
        for (int nt = 0; nt < 2; ++nt)
            w2f[kc][nt] = *(const bf8v*)(W2f + (((kc * 8) + (w * 2 + nt)) * 64 + lane) * 8);
    int col0 = w * 32 + (lane & 15);
    float b2a = bm2[col0], b2b = bm2[col0 + 16];

    __syncthreads();   // Hs ready

    // ---- GEMM2: [64x128] @ [128x32-slice] ----
    f4v acc2[4][2];
    #pragma unroll
    for (int mt = 0; mt < 4; ++mt)
        #pragma unroll
        for (int nt = 0; nt < 2; ++nt)
            acc2[mt][nt] = (f4v){0.f, 0.f, 0.f, 0.f};
    #pragma unroll
    for (int kc = 0; kc < 4; ++kc) {
        bf8v a[4];
        int kb = kc * 64 + (lane >> 4) * 16;
        #pragma unroll
        for (int mt = 0; mt < 4; ++mt) {
            int row = mt * 16 + (lane & 15);
            a[mt] = *(const bf8v*)(Hs + ((row * 256 + kb) ^ ((row & 7) << 4)));
        }
        #pragma unroll
        for (int mt = 0; mt < 4; ++mt)
            #pragma unroll
            for (int nt = 0; nt < 2; ++nt)
                acc2[mt][nt] = __builtin_amdgcn_mfma_f32_16x16x32_bf16(a[mt], w2f[kc][nt], acc2[mt][nt], 0, 0, 0);
    }
    __syncthreads();   // all waves done reading Hs; overlay Ms

    // ---- park messages (bias + bf16) into Ms (= Hs) ----
    #pragma unroll
    for (int mt = 0; mt < 4; ++mt)
        #pragma unroll
        for (int nt = 0; nt < 2; ++nt) {
            int col = col0 + nt * 16;
            float bb = nt ? b2b : b2a;
            #pragma unroll
            for (int r = 0; r < 4; ++r) {
                int row = mt * 16 + (lane >> 4) * 4 + r;
                *(short*)(Hs + ((row * 256 + col * 2) ^ ((row & 7) << 4))) = f2bf_s(acc2[mt][nt][r] + bb);
            }
        }
    __syncthreads();   // Ms + rows_s ready

    // ---- segmented reduce over sorted dests: 256 threads, 1 col x 32 rows each ----
    {
        int col = tid & 127;
        int r0 = (tid >> 7) * 32;
        int cur = rows_s[r0];
        float run = 0.f;
        for (int k = 0; k < 32; ++k) {
            int row = r0 + k;
            int d = rows_s[row];
            unsigned short sv = *(const unsigned short*)(Hs + ((row * 256 + col * 2) ^ ((row & 7) << 4)));
            union { unsigned int u; float f; } c; c.u = ((unsigned int)sv) << 16;
            if (d != cur) {
                unsafeAtomicAdd(aggr + (size_t)cur * DD + col, run);
                run = 0.f; cur = d;
            }
            run += c.f;
        }
        unsafeAtomicAdd(aggr + (size_t)cur * DD + col, run);
    }
}

// ---------------- node kernel: update MLP + residual + LayerNorm ----------------
__global__ __launch_bounds__(256, 4) void node_kernel(
    const float* __restrict__ x, const float* __restrict__ aggr,
    const short* __restrict__ U1f, const short* __restrict__ U2f,
    const float* __restrict__ bu1, const float* __restrict__ bu2,
    const float* __restrict__ gmm, const float* __restrict__ bta,
    float* __restrict__ out)
{
    __shared__ char smem[64 * 512 + 2048];
    char* As = smem;
    float* ps  = (float*)(smem + 64 * 512);
    float* ps2 = ps + 256;

    const int tid = threadIdx.x;
    const int w = tid >> 6, lane = tid & 63;
    const int rbase = blockIdx.x * 64;
    const int rloc = tid >> 2, s = tid & 3;

    {
        int rg = rbase + rloc;
        int rgc = rg < NN ? rg : 0;
        const float* xr = x + (size_t)rgc * DD + s * 32;
        const float* ar = aggr + (size_t)rgc * DD + s * 32;
        int swz = (rloc & 7) << 4;
        #pragma unroll
        for (int i2 = 0; i2 < 4; ++i2) {
            f4v a0 = *(const f4v*)(xr + i2 * 8);
            f4v a1 = *(const f4v*)(xr + i2 * 8 + 4);
            int addr = rloc * 512 + s * 64 + i2 * 16;
            *(u4v*)(As + (addr ^ swz)) = pack8(a0, a1);
            f4v b0 = *(const f4v*)(ar + i2 * 8);
            f4v b1 = *(const f4v*)(ar + i2 * 8 + 4);
            int addr2 = rloc * 512 + 256 + s * 64 + i2 * 16;
            *(u4v*)(As + (addr2 ^ swz)) = pack8(b0, b1);
        }
    }

    bf8v u1f[8][2], u2f[4][2];
    #pragma unroll
    for (int kc = 0; kc < 8; ++kc)
        #pragma unroll
        for (int nt = 0; nt < 2; ++nt)
            u1f[kc][nt] = *(const bf8v*)(U1f + (((kc * 8) + (w * 2 + nt)) * 64 + lane) * 8);
    #pragma unroll
    for (int kc = 0; kc < 4; ++kc)
        #pragma unroll
        for (int nt = 0; nt < 2; ++nt)
            u2f[kc][nt] = *(const bf8v*)(U2f + (((kc * 8) + (w * 2 + nt)) * 64 + lane) * 8);

    __syncthreads();

    f4v acc[4][2];
    #pragma unroll
    for (int mt = 0; mt < 4; ++mt)
        #pragma unroll
        for (int nt = 0; nt < 2; ++nt)
            acc[mt][nt] = (f4v){0.f, 0.f, 0.f, 0.f};
    #pragma unroll
    for (int kc = 0; kc < 8; ++kc) {
        bf8v a[4];
        int kb = kc * 64 + (lane >> 4) * 16;
        #pragma unroll
        for (int mt = 0; mt < 4; ++mt) {
            int row = mt * 16 + (lane & 15);
            a[mt] = *(const bf8v*)(As + ((row * 512 + kb) ^ ((row & 7) << 4)));
        }
        #pragma unroll
        for (int mt = 0; mt < 4; ++mt)
            #pragma unroll
            for (int nt = 0; nt < 2; ++nt)
                acc[mt][nt] = __builtin_amdgcn_mfma_f32_16x16x32_bf16(a[mt], u1f[kc][nt], acc[mt][nt], 0, 0, 0);
    }
    __syncthreads();

    int col0 = w * 32 + (lane & 15);
    float b1a = bu1[col0], b1b = bu1[col0 + 16];
    #pragma unroll
    for (int mt = 0; mt < 4; ++mt)
        #pragma unroll
        for (int nt = 0; nt < 2; ++nt) {
            float bb = nt ? b1b : b1a;
            int col = col0 + nt * 16;
            #pragma unroll
            for (int r = 0; r < 4; ++r) {
                float v = silu(acc[mt][nt][r] + bb);
                int row = mt * 16 + (lane >> 4) * 4 + r;
                *(short*)(As + ((row * 256 + col * 2) ^ ((row & 7) << 4))) = f2bf_s(v);
            }
        }
    __syncthreads();

    f4v acc2[4][2];
    #pragma unroll
    for (int mt = 0; mt < 4; ++mt)
        #pragma unroll
        for (int nt = 0; nt < 2; ++nt)
            acc2[mt][nt] = (f4v){0.f, 0.f, 0.f, 0.f};
    #pragma unroll
    for (int kc = 0; kc < 4; ++kc) {
        bf8v a[4];
        int kb = kc * 64 + (lane >> 4) * 16;
        #pragma unroll
        for (int mt = 0; mt < 4; ++mt) {
            int row = mt * 16 + (lane & 15);
            a[mt] = *(const bf8v*)(As + ((row * 256 + kb) ^ ((row & 7) << 4)));
        }
        #pragma unroll
        for (int mt = 0; mt < 4; ++mt)
            #pragma unroll
            for (int nt = 0; nt < 2; ++nt)
                acc2[mt][nt] = __builtin_amdgcn_mfma_f32_16x16x32_bf16(a[mt], u2f[kc][nt], acc2[mt][nt], 0, 0, 0);
    }
    __syncthreads();

    float b2a = bu2[col0], b2b = bu2[col0 + 16];
    #pragma unroll
    for (int mt = 0; mt < 4; ++mt)
        #pragma unroll
        for (int nt = 0; nt < 2; ++nt) {
            int col = col0 + nt * 16;
            float bb = nt ? b2b : b2a;
            #pragma unroll
            for (int r = 0; r < 4; ++r) {
                int rowl = mt * 16 + (lane >> 4) * 4 + r;
                int rg = rbase + rowl;
                int rgc = rg < NN ? rg : 0;
                float xv = x[(size_t)rgc * DD + col];
                float y = acc2[mt][nt][r] + bb + xv;
                *(float*)(As + ((rowl * 512 + col * 4) ^ ((rowl & 7) << 4))) = y;
            }
        }
    __syncthreads();

    {
        int q = tid & 3;
        float s1 = 0.f, s2 = 0.f;
        #pragma unroll
        for (int i = 0; i < 8; ++i) {
            f4v v = *(const f4v*)(As + ((rloc * 512 + q * 128 + i * 16) ^ ((rloc & 7) << 4)));
            s1 += v[0] + v[1] + v[2] + v[3];
            s2 += v[0] * v[0] + v[1] * v[1] + v[2] * v[2] + v[3] * v[3];
        }
        ps[rloc * 4 + q] = s1;
        ps2[rloc * 4 + q] = s2;
    }
    __syncthreads();
    {
        int q = tid & 3;
        float fs  = ps[rloc * 4] + ps[rloc * 4 + 1] + ps[rloc * 4 + 2] + ps[rloc * 4 + 3];
        float fs2 = ps2[rloc * 4] + ps2[rloc * 4 + 1] + ps2[rloc * 4 + 2] + ps2[rloc * 4 + 3];
        float mu  = fs * (1.f / 128.f);
        float var = fs2 * (1.f / 128.f) - mu * mu;
        float inv = rsqrtf(var + 1e-5f);
        int rg = rbase + rloc;
        if (rg < NN) {
            #pragma unroll
            for (int i = 0; i < 8; ++i) {
                int col = q * 32 + i * 4;
                f4v v  = *(const f4v*)(As + ((rloc * 512 + col * 4) ^ ((rloc & 7) << 4)));
                f4v gg = *(const f4v*)(gmm + col);
                f4v bb = *(const f4v*)(bta + col);
                f4v o;
                #pragma unroll
                for (int j = 0; j < 4; ++j)
                    o[j] = (v[j] - mu) * inv * gg[j] + bb[j];
                *(f4v*)(out + (size_t)rg * DD + col) = o;
            }
        }
    }
}

extern "C" void kernel_launch(void* const* d_in, const int* in_sizes, int n_in,
                              void* d_out, int out_size, void* d_ws, size_t ws_size,
                              hipStream_t stream) {
    const float* x    = (const float*)d_in[0];
    const int*   ei   = (const int*)d_in[1];
    const float* wm1  = (const float*)d_in[2];
    const float* bm1  = (const float*)d_in[3];
    const float* wm2  = (const float*)d_in[4];
    const float* bm2  = (const float*)d_in[5];
    const float* wu1  = (const float*)d_in[6];
    const float* bu1  = (const float*)d_in[7];
    const float* wu2  = (const float*)d_in[8];
    const float* bu2  = (const float*)d_in[9];
    const float* gmm  = (const float*)d_in[10];
    const float* bta  = (const float*)d_in[11];
    float* out = (float*)d_out;

    // ws layout (bytes)
    const size_t off_P     = 0;                       // 12,800,000 (bf16 [N][128])
    const size_t off_Q     = 12800000;                // 12,800,000
    const size_t off_frags = 25600000;                // 196,608
    const size_t off_cnt   = 25796608;                // 200,000
    const size_t off_cur   = 25996608;                // 200,000
    const size_t off_bsum  = 26196608;                // 1,024
    const size_t off_bscan = 26197632;                // 1,024
    const size_t off_rows  = 26198656;                // 3,200,000
    const size_t off_srtc  = 29398656;                // 3,200,000
    const size_t off_rank  = 32598656;                // 3,200,000
    const size_t need_rank   = 35798656;
    const size_t need_atomic = 32598656;

    char* wsB = (char*)d_ws;
    short* P    = (short*)(wsB + off_P);
    short* Q    = (short*)(wsB + off_Q);
    short* Wf   = (short*)(wsB + off_frags);   // [W1f | W2f | U1f | U2f]
    short* W1f  = Wf;
    short* W2f  = Wf + 32768;
    short* U1f  = Wf + 49152;
    short* U2f  = Wf + 81920;
    int*   cnt    = (int*)(wsB + off_cnt);
    int*   cursor = (int*)(wsB + off_cur);
    int*   bsum   = (int*)(wsB + off_bsum);
    int*   bscan  = (int*)(wsB + off_bscan);
    int*   rows   = (int*)(wsB + off_rows);
    int*   srtc   = (int*)(wsB + off_srtc);
    int*   rank   = (int*)(wsB + off_rank);

    // aggr lives in d_out: edge atomics complete before node; node block b reads only
    // its own aggr rows (staged before any out write); blocks own disjoint rows.
    float* aggr = (float*)d_out;

    int tier = (ws_size >= need_rank) ? 2 : (ws_size >= need_atomic ? 1 : 0);

    setup_kernel<<<384, 256, 0, stream>>>(wm1, wm2, wu1, wu2, Wf, cnt, aggr);

    int use_sorted = 0;
    if (tier > 0) {
        hist_rank_kernel<<<(EE + 255) / 256, 256, 0, stream>>>(ei, cnt,
            tier == 2 ? rank : srtc /* scratch, overwritten later */);
        scanA_kernel<<<NB_SCAN, 256, 0, stream>>>(cnt, bsum);
        scanB_kernel<<<1, 256, 0, stream>>>(bsum, bscan);
        scanC_kernel<<<NB_SCAN, 256, 0, stream>>>(cnt, bscan, cursor, rows);
        if (tier == 2)
            scatter_col_rank_kernel<<<(EE + 255) / 256, 256, 0, stream>>>(ei, cursor, rank, srtc);
        else
            scatter_col_atomic_kernel<<<(EE + 255) / 256, 256, 0, stream>>>(ei, cursor, srtc);
        use_sorted = 1;
    }

    // pq last before edge: keeps P/Q warmest in L2/L3 for the gather storm
    pq_kernel<<<(NN + 63) / 64, 256, 0, stream>>>(x, W1f, bm1, P, Q);

    edge_kernel<<<TILES, 256, 0, stream>>>(P, Q, rows, srtc, ei, use_sorted, W2f, bm2, aggr);
    node_kernel<<<(NN + 63) / 64, 256, 0, stream>>>(x, aggr, U1f, U2f, bu1, bu2, gmm, bta, out);
}

// Round 9
// 191.895 us; speedup vs baseline: 1.3659x; 1.0243x over previous
//
#include <hip/hip_runtime.h>
#include <hip/hip_bf16.h>

#define NN 50000
#define EE 800000
#define DD 128
#define TILES (EE / 64)              // 12500
#define NB_SCAN ((NN + 255) / 256)   // 196
#define HIST_BLKS ((EE + 255) / 256) // 3125
#define FRAG_BLKS 384
#define PQ_BLKS ((NN + 63) / 64)     // 782

typedef __attribute__((ext_vector_type(8))) short bf8v;        // 8 bf16
typedef __attribute__((ext_vector_type(4))) float f4v;         // 4 f32
typedef __attribute__((ext_vector_type(4))) unsigned int u4v;  // 16B

static __device__ __forceinline__ unsigned int bpack2(float lo, float hi) {
    union { __hip_bfloat162 h2; unsigned int u; } c;
    c.h2 = __float22bfloat162_rn(float2{lo, hi});   // v_cvt_pk_bf16_f32
    return c.u;
}
static __device__ __forceinline__ u4v pack8(f4v a, f4v b) {
    u4v r;
    r[0] = bpack2(a[0], a[1]); r[1] = bpack2(a[2], a[3]);
    r[2] = bpack2(b[0], b[1]); r[3] = bpack2(b[2], b[3]);
    return r;
}
static __device__ __forceinline__ short f2bf_s(float f) {
    union { __hip_bfloat16 h; short s; } c;
    c.h = __float2bfloat16(f);
    return c.s;
}
static __device__ __forceinline__ float bf_lo(unsigned int u) {
    union { unsigned int u; float f; } c; c.u = u << 16; return c.f;
}
static __device__ __forceinline__ float bf_hi(unsigned int u) {
    union { unsigned int u; float f; } c; c.u = u & 0xffff0000u; return c.f;
}
static __device__ __forceinline__ float silu(float v) {
    return v * __builtin_amdgcn_rcpf(1.f + __expf(-v));
}

// ---- mega1: [blocks 0..3124] hist+rank  ||  [blocks 3125..3508] weight repack + aggr zero ----
__global__ __launch_bounds__(256) void mega1_kernel(
    const int* __restrict__ ei, int* __restrict__ cnt, int* __restrict__ rank, int do_sort,
    const float* __restrict__ wm1, const float* __restrict__ wm2,
    const float* __restrict__ wu1, const float* __restrict__ wu2,
    short* __restrict__ wf, float* __restrict__ aggr)
{
    int b = blockIdx.x;
    if (b < HIST_BLKS) {
        if (do_sort) {
            int e = b * 256 + threadIdx.x;
            if (e < EE) rank[e] = atomicAdd(&cnt[ei[e]], 1);
        }
        return;
    }
    int idx = (b - HIST_BLKS) * 256 + threadIdx.x;   // 0 .. 98303
    {
        const float* src; int l;
        if      (idx < 32768) { src = wm1; l = idx; }
        else if (idx < 49152) { src = wm2; l = idx - 32768; }
        else if (idx < 81920) { src = wu1; l = idx - 49152; }
        else                  { src = wu2; l = idx - 81920; }
        int e    = l & 7;
        int lane = (l >> 3) & 63;
        int ntg  = (l >> 9) & 7;
        int kc   = l >> 12;
        wf[idx] = f2bf_s(src[(kc * 32 + (lane >> 4) * 8 + e) * DD + ntg * 16 + (lane & 15)]);
    }
    f4v z = (f4v){0.f, 0.f, 0.f, 0.f};
    for (int i = idx; i < NN * DD / 4; i += FRAG_BLKS * 256) ((f4v*)aggr)[i] = z;
}

// ---- scanA: per-block sums of cnt ----
__global__ __launch_bounds__(256) void scanA_kernel(const int* __restrict__ cnt,
                                                    int* __restrict__ bsum) {
    __shared__ int sd[256];
    int t = threadIdx.x;
    int i = blockIdx.x * 256 + t;
    sd[t] = (i < NN) ? cnt[i] : 0;
    __syncthreads();
    for (int off = 128; off > 0; off >>= 1) {
        if (t < off) sd[t] += sd[t + off];
        __syncthreads();
    }
    if (t == 0) bsum[blockIdx.x] = sd[0];
}

// ---- scanC2: in-block scan of bsum (replaces scanB) + cursor + u16 rows fill ----
__global__ __launch_bounds__(256) void scanC2_kernel(const int* __restrict__ cnt,
                                                     const int* __restrict__ bsum,
                                                     int* __restrict__ cursor,
                                                     unsigned short* __restrict__ rows16) {
    __shared__ int sb[256];
    __shared__ int sd[256];
    int t = threadIdx.x;
    sb[t] = (t < NB_SCAN) ? bsum[t] : 0;
    __syncthreads();
    for (int off = 1; off < 256; off <<= 1) {
        int u = (t >= off) ? sb[t - off] : 0;
        __syncthreads();
        sb[t] += u;
        __syncthreads();
    }
    int blockpre = (blockIdx.x == 0) ? 0 : sb[blockIdx.x - 1];
    __syncthreads();
    int i = blockIdx.x * 256 + t;
    int v = (i < NN) ? cnt[i] : 0;
    sd[t] = v;
    __syncthreads();
    for (int off = 1; off < 256; off <<= 1) {
        int u = (t >= off) ? sd[t - off] : 0;
        __syncthreads();
        sd[t] += u;
        __syncthreads();
    }
    if (i < NN) {
        int c0 = blockpre + sd[t] - v;
        cursor[i] = c0;
        for (int k = 0; k < v; ++k) rows16[c0 + k] = (unsigned short)i;
    }
}

// ---- mega2: [blocks 0..3124] conflict-free u16 col scatter  ||  [3125..3906] pq ----
__global__ __launch_bounds__(256) void mega2_kernel(
    const int* __restrict__ ei, const int* __restrict__ cursor, const int* __restrict__ rank,
    unsigned short* __restrict__ srtc16, int do_sort,
    const float* __restrict__ x, const short* __restrict__ W1f, const float* __restrict__ bm1,
    short* __restrict__ P, short* __restrict__ Q)
{
    __shared__ char smem[32768];     // pq: x-tile bf16 (16KB) -> Pst @0 ; Qst @16384
    int b = blockIdx.x;
    if (b < HIST_BLKS) {
        if (do_sort) {
            int e = b * 256 + threadIdx.x;
            if (e < EE) srtc16[cursor[ei[e]] + rank[e]] = (unsigned short)ei[EE + e];
        }
        return;
    }
    // ---------------- pq: P = bf16(x@W1top + bm1), Q = bf16(x@W1bot) ----------------
    const int tid = threadIdx.x;
    const int w = tid >> 6, lane = tid & 63;
    const int rbase = (b - HIST_BLKS) * 64;
    const int rloc = tid >> 2, s = tid & 3;

    {   // stage x tile f32 -> bf16 LDS
        int rg = rbase + rloc;
        int rgc = rg < NN ? rg : NN - 1;
        const float* xr = x + (size_t)rgc * DD + s * 32;
        int swz = (rloc & 7) << 4;
        #pragma unroll
        for (int j = 0; j < 4; ++j) {
            f4v a0 = *(const f4v*)(xr + j * 8);
            f4v a1 = *(const f4v*)(xr + j * 8 + 4);
            *(u4v*)(smem + ((rloc * 256 + s * 64 + j * 16) ^ swz)) = pack8(a0, a1);
        }
    }

    bf8v w1t[4][2], w1b[4][2];
    #pragma unroll
    for (int kc = 0; kc < 4; ++kc)
        #pragma unroll
        for (int nt = 0; nt < 2; ++nt) {
            w1t[kc][nt] = *(const bf8v*)(W1f + (((kc * 8) + (w * 2 + nt)) * 64 + lane) * 8);
            w1b[kc][nt] = *(const bf8v*)(W1f + ((((kc + 4) * 8) + (w * 2 + nt)) * 64 + lane) * 8);
        }
    __syncthreads();

    f4v accP[4][2], accQ[4][2];
    #pragma unroll
    for (int mt = 0; mt < 4; ++mt)
        #pragma unroll
        for (int nt = 0; nt < 2; ++nt) {
            accP[mt][nt] = (f4v){0.f, 0.f, 0.f, 0.f};
            accQ[mt][nt] = (f4v){0.f, 0.f, 0.f, 0.f};
        }
    #pragma unroll
    for (int kc = 0; kc < 4; ++kc) {
        bf8v a[4];
        int kb = kc * 64 + (lane >> 4) * 16;
        #pragma unroll
        for (int mt = 0; mt < 4; ++mt) {
            int row = mt * 16 + (lane & 15);
            a[mt] = *(const bf8v*)(smem + ((row * 256 + kb) ^ ((row & 7) << 4)));
        }
        #pragma unroll
        for (int mt = 0; mt < 4; ++mt)
            #pragma unroll
            for (int nt = 0; nt < 2; ++nt) {
                accP[mt][nt] = __builtin_amdgcn_mfma_f32_16x16x32_bf16(a[mt], w1t[kc][nt], accP[mt][nt], 0, 0, 0);
                accQ[mt][nt] = __builtin_amdgcn_mfma_f32_16x16x32_bf16(a[mt], w1b[kc][nt], accQ[mt][nt], 0, 0, 0);
            }
    }
    __syncthreads();   // done reading x-tile

    int col0 = w * 32 + (lane & 15);
    float b1a = bm1[col0], b1b = bm1[col0 + 16];
    #pragma unroll
    for (int mt = 0; mt < 4; ++mt)
        #pragma unroll
        for (int nt = 0; nt < 2; ++nt) {
            float bb = nt ? b1b : b1a;
            int col = col0 + nt * 16;
            #pragma unroll
            for (int r = 0; r < 4; ++r) {
                int row = mt * 16 + (lane >> 4) * 4 + r;
                int off = (row * 256 + col * 2) ^ ((row & 7) << 4);
                *(short*)(smem + off)         = f2bf_s(accP[mt][nt][r] + bb);
                *(short*)(smem + 16384 + off) = f2bf_s(accQ[mt][nt][r]);
            }
        }
    __syncthreads();

    {   // coalesced store P,Q
        int rg = rbase + rloc;
        if (rg < NN) {
            int swz = (rloc & 7) << 4;
            #pragma unroll
            for (int j = 0; j < 4; ++j) {
                int off = (rloc * 256 + s * 64 + j * 16) ^ swz;
                *(u4v*)(P + (size_t)rg * DD + s * 32 + j * 8) = *(const u4v*)(smem + off);
                *(u4v*)(Q + (size_t)rg * DD + s * 32 + j * 8) = *(const u4v*)(smem + 16384 + off);
            }
        }
    }
}

// ---------------- edge kernel: one 64-edge tile per block, Ms overlays Hs ----------------
// h = silu(P[r]+Q[c]); msg = h@W2 + bm2; segmented scatter-add over sorted dests
__global__ __launch_bounds__(256, 8) void edge_kernel(
    const short* __restrict__ P, const short* __restrict__ Q,
    const unsigned short* __restrict__ rows16, const unsigned short* __restrict__ srtc16,
    const int* __restrict__ ei, int use_sorted,
    const short* __restrict__ W2f, const float* __restrict__ bm2,
    float* __restrict__ aggr)
{
    __shared__ char smem[16384 + 256];
    char* Hs = smem;                 // [64][128] bf16 swizzled; reused as Ms after GEMM2
    int* rows_s = (int*)(smem + 16384);

    const int tid = threadIdx.x;
    const int w = tid >> 6, lane = tid & 63;
    const int rloc = tid >> 2, s = tid & 3;

    // ---- stage: gather P[r], Q[c], h = silu(P+Q) -> Hs ----
    {
        int eg = blockIdx.x * 64 + rloc;
        int r, c;
        if (use_sorted) { r = rows16[eg]; c = srtc16[eg]; }
        else            { r = ei[eg];     c = ei[EE + eg]; }
        if (s == 0) rows_s[rloc] = r;
        const u4v* pr = (const u4v*)(P + (size_t)r * DD + s * 32);
        const u4v* qr = (const u4v*)(Q + (size_t)c * DD + s * 32);
        int swz = (rloc & 7) << 4;
        #pragma unroll
        for (int j = 0; j < 4; ++j) {
            u4v pj = pr[j], qj = qr[j];
            u4v hv;
            #pragma unroll
            for (int k2 = 0; k2 < 4; ++k2) {
                float lo = silu(bf_lo(pj[k2]) + bf_lo(qj[k2]));
                float hi = silu(bf_hi(pj[k2]) + bf_hi(qj[k2]));
                hv[k2] = bpack2(lo, hi);
            }
            *(u4v*)(Hs + ((rloc * 256 + s * 64 + j * 16) ^ swz)) = hv;
        }
    }

    // weight fragments (independent of stage; overlaps gather latency)
    bf8v w2f[4][2];
    #pragma unroll
    for (int kc = 0; kc < 4; ++kc)
        #pragma unroll
        for (int nt = 0; nt < 2; ++nt)
            w2f[kc][nt] = *(const bf8v*)(W2f + (((kc * 8) + (w * 2 + nt)) * 64 + lane) * 8);
    int col0 = w * 32 + (lane & 15);
    float b2a = bm2[col0], b2b = bm2[col0 + 16];

    __syncthreads();   // Hs ready

    // ---- GEMM2: [64x128] @ [128x32-slice] ----
    f4v acc2[4][2];
    #pragma unroll
    for (int mt = 0; mt < 4; ++mt)
        #pragma unroll
        for (int nt = 0; nt < 2; ++nt)
            acc2[mt][nt] = (f4v){0.f, 0.f, 0.f, 0.f};
    #pragma unroll
    for (int kc = 0; kc < 4; ++kc) {
        bf8v a[4];
        int kb = kc * 64 + (lane >> 4) * 16;
        #pragma unroll
        for (int mt = 0; mt < 4; ++mt) {
            int row = mt * 16 + (lane & 15);
            a[mt] = *(const bf8v*)(Hs + ((row * 256 + kb) ^ ((row & 7) << 4)));
        }
        #pragma unroll
        for (int mt = 0; mt < 4; ++mt)
            #pragma unroll
            for (int nt = 0; nt < 2; ++nt)
                acc2[mt][nt] = __builtin_amdgcn_mfma_f32_16x16x32_bf16(a[mt], w2f[kc][nt], acc2[mt][nt], 0, 0, 0);
    }
    __syncthreads();   // all waves done reading Hs; overlay Ms

    // ---- park messages (bias + bf16) into Ms (= Hs) ----
    #pragma unroll
    for (int mt = 0; mt < 4; ++mt)
        #pragma unroll
        for (int nt = 0; nt < 2; ++nt) {
            int col = col0 + nt * 16;
            float bb = nt ? b2b : b2a;
            #pragma unroll
            for (int r = 0; r < 4; ++r) {
                int row = mt * 16 + (lane >> 4) * 4 + r;
                *(short*)(Hs + ((row * 256 + col * 2) ^ ((row & 7) << 4))) = f2bf_s(acc2[mt][nt][r] + bb);
            }
        }
    __syncthreads();   // Ms + rows_s ready

    // ---- segmented reduce over sorted dests: 256 threads, 1 col x 32 rows each ----
    {
        int col = tid & 127;
        int r0 = (tid >> 7) * 32;
        int cur = rows_s[r0];
        float run = 0.f;
        for (int k = 0; k < 32; ++k) {
            int row = r0 + k;
            int d = rows_s[row];
            unsigned short sv = *(const unsigned short*)(Hs + ((row * 256 + col * 2) ^ ((row & 7) << 4)));
            union { unsigned int u; float f; } c; c.u = ((unsigned int)sv) << 16;
            if (d != cur) {
                unsafeAtomicAdd(aggr + (size_t)cur * DD + col, run);
                run = 0.f; cur = d;
            }
            run += c.f;
        }
        unsafeAtomicAdd(aggr + (size_t)cur * DD + col, run);
    }
}

// ---------------- node kernel: update MLP + residual + LayerNorm ----------------
__global__ __launch_bounds__(256, 4) void node_kernel(
    const float* __restrict__ x, const float* __restrict__ aggr,
    const short* __restrict__ U1f, const short* __restrict__ U2f,
    const float* __restrict__ bu1, const float* __restrict__ bu2,
    const float* __restrict__ gmm, const float* __restrict__ bta,
    float* __restrict__ out)
{
    __shared__ char smem[64 * 512 + 2048];
    char* As = smem;
    float* ps  = (float*)(smem + 64 * 512);
    float* ps2 = ps + 256;

    const int tid = threadIdx.x;
    const int w = tid >> 6, lane = tid & 63;
    const int rbase = blockIdx.x * 64;
    const int rloc = tid >> 2, s = tid & 3;

    {
        int rg = rbase + rloc;
        int rgc = rg < NN ? rg : 0;
        const float* xr = x + (size_t)rgc * DD + s * 32;
        const float* ar = aggr + (size_t)rgc * DD + s * 32;
        int swz = (rloc & 7) << 4;
        #pragma unroll
        for (int i2 = 0; i2 < 4; ++i2) {
            f4v a0 = *(const f4v*)(xr + i2 * 8);
            f4v a1 = *(const f4v*)(xr + i2 * 8 + 4);
            int addr = rloc * 512 + s * 64 + i2 * 16;
            *(u4v*)(As + (addr ^ swz)) = pack8(a0, a1);
            f4v b0 = *(const f4v*)(ar + i2 * 8);
            f4v b1 = *(const f4v*)(ar + i2 * 8 + 4);
            int addr2 = rloc * 512 + 256 + s * 64 + i2 * 16;
            *(u4v*)(As + (addr2 ^ swz)) = pack8(b0, b1);
        }
    }

    bf8v u1f[8][2], u2f[4][2];
    #pragma unroll
    for (int kc = 0; kc < 8; ++kc)
        #pragma unroll
        for (int nt = 0; nt < 2; ++nt)
            u1f[kc][nt] = *(const bf8v*)(U1f + (((kc * 8) + (w * 2 + nt)) * 64 + lane) * 8);
    #pragma unroll
    for (int kc = 0; kc < 4; ++kc)
        #pragma unroll
        for (int nt = 0; nt < 2; ++nt)
            u2f[kc][nt] = *(const bf8v*)(U2f + (((kc * 8) + (w * 2 + nt)) * 64 + lane) * 8);

    __syncthreads();

    f4v acc[4][2];
    #pragma unroll
    for (int mt = 0; mt < 4; ++mt)
        #pragma unroll
        for (int nt = 0; nt < 2; ++nt)
            acc[mt][nt] = (f4v){0.f, 0.f, 0.f, 0.f};
    #pragma unroll
    for (int kc = 0; kc < 8; ++kc) {
        bf8v a[4];
        int kb = kc * 64 + (lane >> 4) * 16;
        #pragma unroll
        for (int mt = 0; mt < 4; ++mt) {
            int row = mt * 16 + (lane & 15);
            a[mt] = *(const bf8v*)(As + ((row * 512 + kb) ^ ((row & 7) << 4)));
        }
        #pragma unroll
        for (int mt = 0; mt < 4; ++mt)
            #pragma unroll
            for (int nt = 0; nt < 2; ++nt)
                acc[mt][nt] = __builtin_amdgcn_mfma_f32_16x16x32_bf16(a[mt], u1f[kc][nt], acc[mt][nt], 0, 0, 0);
    }
    __syncthreads();

    int col0 = w * 32 + (lane & 15);
    float b1a = bu1[col0], b1b = bu1[col0 + 16];
    #pragma unroll
    for (int mt = 0; mt < 4; ++mt)
        #pragma unroll
        for (int nt = 0; nt < 2; ++nt) {
            float bb = nt ? b1b : b1a;
            int col = col0 + nt * 16;
            #pragma unroll
            for (int r = 0; r < 4; ++r) {
                float v = silu(acc[mt][nt][r] + bb);
                int row = mt * 16 + (lane >> 4) * 4 + r;
                *(short*)(As + ((row * 256 + col * 2) ^ ((row & 7) << 4))) = f2bf_s(v);
            }
        }
    __syncthreads();

    f4v acc2[4][2];
    #pragma unroll
    for (int mt = 0; mt < 4; ++mt)
        #pragma unroll
        for (int nt = 0; nt < 2; ++nt)
            acc2[mt][nt] = (f4v){0.f, 0.f, 0.f, 0.f};
    #pragma unroll
    for (int kc = 0; kc < 4; ++kc) {
        bf8v a[4];
        int kb = kc * 64 + (lane >> 4) * 16;
        #pragma unroll
        for (int mt = 0; mt < 4; ++mt) {
            int row = mt * 16 + (lane & 15);
            a[mt] = *(const bf8v*)(As + ((row * 256 + kb) ^ ((row & 7) << 4)));
        }
        #pragma unroll
        for (int mt = 0; mt < 4; ++mt)
            #pragma unroll
            for (int nt = 0; nt < 2; ++nt)
                acc2[mt][nt] = __builtin_amdgcn_mfma_f32_16x16x32_bf16(a[mt], u2f[kc][nt], acc2[mt][nt], 0, 0, 0);
    }
    __syncthreads();

    float b2a = bu2[col0], b2b = bu2[col0 + 16];
    #pragma unroll
    for (int mt = 0; mt < 4; ++mt)
        #pragma unroll
        for (int nt = 0; nt < 2; ++nt) {
            int col = col0 + nt * 16;
            float bb = nt ? b2b : b2a;
            #pragma unroll
            for (int r = 0; r < 4; ++r) {
                int rowl = mt * 16 + (lane >> 4) * 4 + r;
                int rg = rbase + rowl;
                int rgc = rg < NN ? rg : 0;
                float xv = x[(size_t)rgc * DD + col];
                float y = acc2[mt][nt][r] + bb + xv;
                *(float*)(As + ((rowl * 512 + col * 4) ^ ((rowl & 7) << 4))) = y;
            }
        }
    __syncthreads();

    {
        int q = tid & 3;
        float s1 = 0.f, s2 = 0.f;
        #pragma unroll
        for (int i = 0; i < 8; ++i) {
            f4v v = *(const f4v*)(As + ((rloc * 512 + q * 128 + i * 16) ^ ((rloc & 7) << 4)));
            s1 += v[0] + v[1] + v[2] + v[3];
            s2 += v[0] * v[0] + v[1] * v[1] + v[2] * v[2] + v[3] * v[3];
        }
        ps[rloc * 4 + q] = s1;
        ps2[rloc * 4 + q] = s2;
    }
    __syncthreads();
    {
        int q = tid & 3;
        float fs  = ps[rloc * 4] + ps[rloc * 4 + 1] + ps[rloc * 4 + 2] + ps[rloc * 4 + 3];
        float fs2 = ps2[rloc * 4] + ps2[rloc * 4 + 1] + ps2[rloc * 4 + 2] + ps2[rloc * 4 + 3];
        float mu  = fs * (1.f / 128.f);
        float var = fs2 * (1.f / 128.f) - mu * mu;
        float inv = rsqrtf(var + 1e-5f);
        int rg = rbase + rloc;
        if (rg < NN) {
            #pragma unroll
            for (int i = 0; i < 8; ++i) {
                int col = q * 32 + i * 4;
                f4v v  = *(const f4v*)(As + ((rloc * 512 + col * 4) ^ ((rloc & 7) << 4)));
                f4v gg = *(const f4v*)(gmm + col);
                f4v bb = *(const f4v*)(bta + col);
                f4v o;
                #pragma unroll
                for (int j = 0; j < 4; ++j)
                    o[j] = (v[j] - mu) * inv * gg[j] + bb[j];
                *(f4v*)(out + (size_t)rg * DD + col) = o;
            }
        }
    }
}

extern "C" void kernel_launch(void* const* d_in, const int* in_sizes, int n_in,
                              void* d_out, int out_size, void* d_ws, size_t ws_size,
                              hipStream_t stream) {
    const float* x    = (const float*)d_in[0];
    const int*   ei   = (const int*)d_in[1];
    const float* wm1  = (const float*)d_in[2];
    const float* bm1  = (const float*)d_in[3];
    const float* wm2  = (const float*)d_in[4];
    const float* bm2  = (const float*)d_in[5];
    const float* wu1  = (const float*)d_in[6];
    const float* bu1  = (const float*)d_in[7];
    const float* wu2  = (const float*)d_in[8];
    const float* bu2  = (const float*)d_in[9];
    const float* gmm  = (const float*)d_in[10];
    const float* bta  = (const float*)d_in[11];
    float* out = (float*)d_out;

    // ws layout (bytes)
    const size_t off_P      = 0;                       // 12,800,000 (bf16 [N][128])
    const size_t off_Q      = 12800000;                // 12,800,000
    const size_t off_frags  = 25600000;                // 196,608
    const size_t off_cnt    = 25796608;                // 200,000
    const size_t off_cur    = 25996608;                // 200,000
    const size_t off_bsum   = 26196608;                // 1,024
    const size_t off_rows16 = 26197632;                // 1,600,000
    const size_t off_srtc16 = 27797632;                // 1,600,000
    const size_t off_rank   = 29397632;                // 3,200,000
    const size_t need_sort  = 32597632;

    char* wsB = (char*)d_ws;
    short* P    = (short*)(wsB + off_P);
    short* Q    = (short*)(wsB + off_Q);
    short* Wf   = (short*)(wsB + off_frags);   // [W1f | W2f | U1f | U2f]
    short* W1f  = Wf;
    short* W2f  = Wf + 32768;
    short* U1f  = Wf + 49152;
    short* U2f  = Wf + 81920;
    int*   cnt    = (int*)(wsB + off_cnt);
    int*   cursor = (int*)(wsB + off_cur);
    int*   bsum   = (int*)(wsB + off_bsum);
    unsigned short* rows16 = (unsigned short*)(wsB + off_rows16);
    unsigned short* srtc16 = (unsigned short*)(wsB + off_srtc16);
    int*   rank   = (int*)(wsB + off_rank);

    // aggr lives in d_out: edge atomics complete before node; node block b reads only
    // its own aggr rows (staged before any out write); blocks own disjoint rows.
    float* aggr = (float*)d_out;

    int do_sort = (ws_size >= need_sort) ? 1 : 0;

    hipMemsetAsync(cnt, 0, (size_t)NN * 4, stream);
    // mega1: hist+rank (ei)  ||  weight repack + aggr zero  — independent, overlapped
    mega1_kernel<<<HIST_BLKS + FRAG_BLKS, 256, 0, stream>>>(
        ei, cnt, rank, do_sort, wm1, wm2, wu1, wu2, Wf, aggr);

    if (do_sort) {
        scanA_kernel<<<NB_SCAN, 256, 0, stream>>>(cnt, bsum);
        scanC2_kernel<<<NB_SCAN, 256, 0, stream>>>(cnt, bsum, cursor, rows16);
    }
    // mega2: u16 col scatter (sort)  ||  pq (x, W1f) — independent, overlapped;
    // pq adjacency to edge_kernel keeps P/Q warm in L2/L3.
    mega2_kernel<<<HIST_BLKS + PQ_BLKS, 256, 0, stream>>>(
        ei, cursor, rank, srtc16, do_sort, x, W1f, bm1, P, Q);

    edge_kernel<<<TILES, 256, 0, stream>>>(P, Q, rows16, srtc16, ei, do_sort, W2f, bm2, aggr);
    node_kernel<<<(NN + 63) / 64, 256, 0, stream>>>(x, aggr, U1f, U2f, bu1, bu2, gmm, bta, out);
}